// Round 1
// baseline (1263.782 us; speedup 1.0000x reference)
//
#include <hip/hip_runtime.h>

#define NN 32768
#define KK 16
#define DD 6

__device__ __forceinline__ float sigm(float x) { return 1.0f / (1.0f + __expf(-x)); }
__device__ __forceinline__ float ftanh(float x) {
    float e = __expf(2.0f * x);
    return 1.0f - 2.0f / (e + 1.0f);
}

// K0: Wx[n, 0:256] = E[labels[n]] @ W_w + W_b
// block = 256 = 4 waves; wave g handles gate g (columns g*64 .. g*64+63).
// W_w column cached in 64 VGPRs/lane; x row is wave-uniform -> scalar loads.
__global__ __launch_bounds__(256) void k0_wx(
    const int* __restrict__ labels, const float* __restrict__ E,
    const float* __restrict__ W_w, const float* __restrict__ W_b,
    float* __restrict__ Wx)
{
    const int t = threadIdx.x & 63;
    const int g = __builtin_amdgcn_readfirstlane((int)(threadIdx.x >> 6));
    float w[64];
#pragma unroll
    for (int d = 0; d < 64; ++d) w[d] = W_w[d * 256 + g * 64 + t];
    const float b = W_b[g * 64 + t];
    for (int n = blockIdx.x; n < NN; n += gridDim.x) {
        const int lab = labels[n];                       // uniform
        const float* __restrict__ x = E + (size_t)lab * 64;  // uniform row
        float a0 = b, a1 = 0.f, a2 = 0.f, a3 = 0.f;
#pragma unroll
        for (int d = 0; d < 64; d += 4) {
            a0 = fmaf(x[d + 0], w[d + 0], a0);
            a1 = fmaf(x[d + 1], w[d + 1], a1);
            a2 = fmaf(x[d + 2], w[d + 2], a2);
            a3 = fmaf(x[d + 3], w[d + 3], a3);
        }
        Wx[(size_t)n * 256 + g * 64 + t] = (a0 + a1) + (a2 + a3);
    }
}

// K1: per node: gather K children, h_sum, branch_f = sum_k sigmoid(Wf_x + h_k@U_f)*c_k.
// One wave per node. U_f column t in 64 VGPRs. Child row pointers wave-uniform ->
// hrow[d] broadcasts become scalar (SMEM) loads. Row 0 of h_prev/c_prev is zero,
// so idx==0 (masked child) contributes 0 automatically -- no mask logic.
__global__ __launch_bounds__(256) void k1_child(
    const int* __restrict__ cidx, const float* __restrict__ h_prev,
    const float* __restrict__ c_prev, const float* __restrict__ Wx,
    const float* __restrict__ U_f,
    float* __restrict__ hsum, float* __restrict__ bfv, int first)
{
    const int t = threadIdx.x & 63;
    const int w = __builtin_amdgcn_readfirstlane((int)(threadIdx.x >> 6));
    float uf[64];
#pragma unroll
    for (int d = 0; d < 64; ++d) uf[d] = U_f[d * 64 + t];
    const int nw = gridDim.x * 4;
    for (int n = blockIdx.x * 4 + w; n < NN; n += nw) {
        float hs = 0.f, bf = 0.f;
        if (!first) {
            const int* __restrict__ ci = cidx + (size_t)n * KK;
            const float wfx = Wx[(size_t)n * 256 + t];
#pragma unroll
            for (int k = 0; k < KK; ++k) {
                const int idx = ci[k];                                  // uniform
                const float* __restrict__ hrow = h_prev + (size_t)idx * 64;
                const float hk = hrow[t];                               // coalesced
                const float ck = c_prev[(size_t)idx * 64 + t];          // coalesced
                hs += hk;
                float a0 = wfx, a1 = 0.f, a2 = 0.f, a3 = 0.f;
#pragma unroll
                for (int d = 0; d < 64; d += 4) {                        // hrow[d]: scalar
                    a0 = fmaf(hrow[d + 0], uf[d + 0], a0);
                    a1 = fmaf(hrow[d + 1], uf[d + 1], a1);
                    a2 = fmaf(hrow[d + 2], uf[d + 2], a2);
                    a3 = fmaf(hrow[d + 3], uf[d + 3], a3);
                }
                const float fk = sigm((a0 + a1) + (a2 + a3));
                bf = fmaf(fk, ck, bf);
            }
        }
        hsum[(size_t)n * 64 + t] = hs;
        bfv[(size_t)n * 64 + t] = bf;
    }
}

// K2: iuo = h_sum @ U_iuo; gates; new_c = i*u + bf; new_h = o*tanh(new_c).
// U_iuo columns (i,u,o) in 192 VGPRs/lane; h_sum row wave-uniform -> scalar loads.
// Writes rows 1..N of next-state buffers (or d_out at last depth); block 0 zeroes row 0.
__global__ __launch_bounds__(256) void k2_out(
    const float* __restrict__ hsum, const float* __restrict__ bfv,
    const float* __restrict__ Wx, const float* __restrict__ U_iuo,
    float* __restrict__ h_next, float* __restrict__ c_next,
    float* __restrict__ out, int last)
{
    const int t = threadIdx.x & 63;
    const int w = __builtin_amdgcn_readfirstlane((int)(threadIdx.x >> 6));
    float ui[64], uu[64], uo[64];
#pragma unroll
    for (int d = 0; d < 64; ++d) {
        ui[d] = U_iuo[d * 192 + t];
        uu[d] = U_iuo[d * 192 + 64 + t];
        uo[d] = U_iuo[d * 192 + 128 + t];
    }
    const int nw = gridDim.x * 4;
    for (int n = blockIdx.x * 4 + w; n < NN; n += nw) {
        const float* __restrict__ hr = hsum + (size_t)n * 64;   // uniform row
        float ai = Wx[(size_t)n * 256 + 64 + t];
        float au = Wx[(size_t)n * 256 + 128 + t];
        float ao = Wx[(size_t)n * 256 + 192 + t];
#pragma unroll
        for (int d = 0; d < 64; ++d) {
            const float hv = hr[d];                              // scalar load
            ai = fmaf(hv, ui[d], ai);
            au = fmaf(hv, uu[d], au);
            ao = fmaf(hv, uo[d], ao);
        }
        const float ig = sigm(ai);
        const float ug = ftanh(au);
        const float og = sigm(ao);
        const float nc = fmaf(ig, ug, bfv[(size_t)n * 64 + t]);
        const float nh = og * ftanh(nc);
        if (last) {
            out[(size_t)n * 64 + t] = nh;
        } else {
            h_next[(size_t)(n + 1) * 64 + t] = nh;
            c_next[(size_t)(n + 1) * 64 + t] = nc;
        }
    }
    if (!last && blockIdx.x == 0 && threadIdx.x < 64) {
        h_next[threadIdx.x] = 0.f;   // zero init-state row: makes idx==0 gather a no-op
        c_next[threadIdx.x] = 0.f;
    }
}

extern "C" void kernel_launch(void* const* d_in, const int* in_sizes, int n_in,
                              void* d_out, int out_size, void* d_ws, size_t ws_size,
                              hipStream_t stream)
{
    const int*   labels = (const int*)d_in[0];    // [6, 32768]
    const int*   child  = (const int*)d_in[1];    // [6, 32768, 16]
    const float* E      = (const float*)d_in[2];  // [100000, 64]
    const float* W_w    = (const float*)d_in[3];  // [64, 256]
    const float* W_b    = (const float*)d_in[4];  // [256]
    const float* U_f    = (const float*)d_in[5];  // [64, 64]
    const float* U_iuo  = (const float*)d_in[6];  // [64, 192]
    float* out = (float*)d_out;
    float* ws  = (float*)d_ws;

    const size_t R = (size_t)(NN + 1) * 64;
    float* h0 = ws;               // state pair 0
    float* c0 = ws + R;
    float* h1 = ws + 2 * R;       // state pair 1
    float* c1 = ws + 3 * R;
    float* Wx = ws + 4 * R;                       // [N, 256]
    float* hs = Wx + (size_t)NN * 256;            // [N, 64]
    float* bf = hs + (size_t)NN * 64;             // [N, 64]

    float* hp = h0; float* cp = c0;
    float* hn = h1; float* cn = c1;
    for (int d = 0; d < DD; ++d) {
        const int last = (d == DD - 1);
        k0_wx<<<512, 256, 0, stream>>>(labels + (size_t)d * NN, E, W_w, W_b, Wx);
        k1_child<<<2048, 256, 0, stream>>>(child + (size_t)d * NN * KK, hp, cp, Wx,
                                           U_f, hs, bf, d == 0);
        k2_out<<<512, 256, 0, stream>>>(hs, bf, Wx, U_iuo, hn, cn, out, last);
        float* th = hp; hp = hn; hn = th;
        float* tc = cp; cp = cn; cn = tc;
    }
}

// Round 2
// 923.369 us; speedup vs baseline: 1.3687x; 1.3687x over previous
//
#include <hip/hip_runtime.h>

#define NN 32768
#define KK 16
#define DD 6

__device__ __forceinline__ float sigm(float x) { return 1.0f / (1.0f + __expf(-x)); }
__device__ __forceinline__ float ftanh(float x) {
    float e = __expf(2.0f * x);
    return 1.0f - 2.0f / (e + 1.0f);
}

// K0: Wx[n, 0:256] = E[labels[n]] @ W_w + W_b
// wave g = gate g. W_w column resident in 64 VGPRs/lane (launch_bounds(256,4)
// allows 128 VGPRs -- the R0 run was capped at ~52 and rematerialized!).
// x row is wave-uniform -> s_load chain.
__global__ __launch_bounds__(256, 4) void k0_wx(
    const int* __restrict__ labels, const float* __restrict__ E,
    const float* __restrict__ W_w, const float* __restrict__ W_b,
    float* __restrict__ Wx)
{
    const int t = threadIdx.x & 63;
    const int g = __builtin_amdgcn_readfirstlane((int)(threadIdx.x >> 6));
    float w[64];
#pragma unroll
    for (int d = 0; d < 64; ++d) w[d] = W_w[d * 256 + g * 64 + t];
    const float b = W_b[g * 64 + t];
    for (int n = blockIdx.x; n < NN; n += gridDim.x) {
        const int lab = labels[n];                           // uniform
        const float* __restrict__ x = E + (size_t)lab * 64;  // uniform row
        float a0 = b, a1 = 0.f, a2 = 0.f, a3 = 0.f;
#pragma unroll
        for (int d = 0; d < 64; d += 4) {
            a0 = fmaf(x[d + 0], w[d + 0], a0);
            a1 = fmaf(x[d + 1], w[d + 1], a1);
            a2 = fmaf(x[d + 2], w[d + 2], a2);
            a3 = fmaf(x[d + 3], w[d + 3], a3);
        }
        Wx[(size_t)n * 256 + g * 64 + t] = (a0 + a1) + (a2 + a3);
    }
}

// K1: pure gather kernel. g_prev[j] = h_prev[j] @ U_f precomputed (kg), so
// per child only: hs += h[idx]; bf += sigm(wfx + g[idx]) * c[idx].
// One wave per node; rows 0 of h/c/g are zero => idx==0 masked for free.
// bf overwrites the consumed Wf_x slot of Wx (saves a buffer).
__global__ void k1_child(
    const int* __restrict__ cidx, const float* __restrict__ h_prev,
    const float* __restrict__ c_prev, const float* __restrict__ g_prev,
    float* __restrict__ Wx, float* __restrict__ hsum, int first)
{
    const int t = threadIdx.x & 63;
    const int w = __builtin_amdgcn_readfirstlane((int)(threadIdx.x >> 6));
    const int n = blockIdx.x * 4 + w;
    float hs = 0.f, bf = 0.f;
    if (!first) {
        const int* __restrict__ ci = cidx + (size_t)n * KK;
        int idx[KK];
#pragma unroll
        for (int k = 0; k < KK; ++k) idx[k] = ci[k];         // uniform s_loads
        const float wfx = Wx[(size_t)n * 256 + t];
#pragma unroll
        for (int k = 0; k < KK; k += 4) {
            const int i0 = idx[k], i1 = idx[k + 1], i2 = idx[k + 2], i3 = idx[k + 3];
            const float h0 = h_prev[(size_t)i0 * 64 + t];
            const float h1 = h_prev[(size_t)i1 * 64 + t];
            const float h2 = h_prev[(size_t)i2 * 64 + t];
            const float h3 = h_prev[(size_t)i3 * 64 + t];
            const float c0 = c_prev[(size_t)i0 * 64 + t];
            const float c1 = c_prev[(size_t)i1 * 64 + t];
            const float c2 = c_prev[(size_t)i2 * 64 + t];
            const float c3 = c_prev[(size_t)i3 * 64 + t];
            const float g0 = g_prev[(size_t)i0 * 64 + t];
            const float g1 = g_prev[(size_t)i1 * 64 + t];
            const float g2 = g_prev[(size_t)i2 * 64 + t];
            const float g3 = g_prev[(size_t)i3 * 64 + t];
            hs += (h0 + h1) + (h2 + h3);
            bf = fmaf(sigm(wfx + g0), c0, bf);
            bf = fmaf(sigm(wfx + g1), c1, bf);
            bf = fmaf(sigm(wfx + g2), c2, bf);
            bf = fmaf(sigm(wfx + g3), c3, bf);
        }
    }
    hsum[(size_t)n * 64 + t] = hs;
    Wx[(size_t)n * 256 + t] = bf;    // branch_f into consumed Wf_x slot
}

// K2: iuo = h_sum @ U_iuo; gates; new_c = i*u + bf; new_h = o*tanh(new_c).
// 192 weight VGPRs resident (launch_bounds(256,2) -> up to 256 VGPRs).
__global__ __launch_bounds__(256, 2) void k2_out(
    const float* __restrict__ hsum, const float* __restrict__ Wx,
    const float* __restrict__ U_iuo,
    float* __restrict__ h_next, float* __restrict__ c_next,
    float* __restrict__ out, int last)
{
    const int t = threadIdx.x & 63;
    const int w = __builtin_amdgcn_readfirstlane((int)(threadIdx.x >> 6));
    float ui[64], uu[64], uo[64];
#pragma unroll
    for (int d = 0; d < 64; ++d) {
        ui[d] = U_iuo[d * 192 + t];
        uu[d] = U_iuo[d * 192 + 64 + t];
        uo[d] = U_iuo[d * 192 + 128 + t];
    }
    const int nw = gridDim.x * 4;
    for (int n = blockIdx.x * 4 + w; n < NN; n += nw) {
        const float* __restrict__ hr = hsum + (size_t)n * 64;   // uniform row
        float ai = Wx[(size_t)n * 256 + 64 + t];
        float au = Wx[(size_t)n * 256 + 128 + t];
        float ao = Wx[(size_t)n * 256 + 192 + t];
#pragma unroll
        for (int d = 0; d < 64; ++d) {
            const float hv = hr[d];                              // s_load
            ai = fmaf(hv, ui[d], ai);
            au = fmaf(hv, uu[d], au);
            ao = fmaf(hv, uo[d], ao);
        }
        const float ig = sigm(ai);
        const float ug = ftanh(au);
        const float og = sigm(ao);
        const float nc = fmaf(ig, ug, Wx[(size_t)n * 256 + t]);  // bf from f-slot
        const float nh = og * ftanh(nc);
        if (last) {
            out[(size_t)n * 64 + t] = nh;
        } else {
            h_next[(size_t)(n + 1) * 64 + t] = nh;
            c_next[(size_t)(n + 1) * 64 + t] = nc;
        }
    }
    if (!last && blockIdx.x == 0 && threadIdx.x < 64) {
        h_next[threadIdx.x] = 0.f;   // zero init-state row -> idx==0 gather is a no-op
        c_next[threadIdx.x] = 0.f;
    }
}

// Kg: g[n] = h_next[n] @ U_f  (the factored-out per-child matvec, once per row)
__global__ __launch_bounds__(256, 4) void kg_gf(
    const float* __restrict__ h_next, const float* __restrict__ U_f,
    float* __restrict__ gbuf)
{
    const int t = threadIdx.x & 63;
    const int w = __builtin_amdgcn_readfirstlane((int)(threadIdx.x >> 6));
    float uf[64];
#pragma unroll
    for (int d = 0; d < 64; ++d) uf[d] = U_f[d * 64 + t];
    const int nw = gridDim.x * 4;
    for (int n = blockIdx.x * 4 + w; n < NN; n += nw) {
        const float* __restrict__ hr = h_next + (size_t)(n + 1) * 64;  // uniform row
        float a0 = 0.f, a1 = 0.f, a2 = 0.f, a3 = 0.f;
#pragma unroll
        for (int d = 0; d < 64; d += 4) {
            a0 = fmaf(hr[d + 0], uf[d + 0], a0);
            a1 = fmaf(hr[d + 1], uf[d + 1], a1);
            a2 = fmaf(hr[d + 2], uf[d + 2], a2);
            a3 = fmaf(hr[d + 3], uf[d + 3], a3);
        }
        gbuf[(size_t)(n + 1) * 64 + t] = (a0 + a1) + (a2 + a3);
    }
    if (blockIdx.x == 0 && threadIdx.x < 64) gbuf[threadIdx.x] = 0.f;  // zero row 0
}

extern "C" void kernel_launch(void* const* d_in, const int* in_sizes, int n_in,
                              void* d_out, int out_size, void* d_ws, size_t ws_size,
                              hipStream_t stream)
{
    const int*   labels = (const int*)d_in[0];    // [6, 32768]
    const int*   child  = (const int*)d_in[1];    // [6, 32768, 16]
    const float* E      = (const float*)d_in[2];  // [100000, 64]
    const float* W_w    = (const float*)d_in[3];  // [64, 256]
    const float* W_b    = (const float*)d_in[4];  // [256]
    const float* U_f    = (const float*)d_in[5];  // [64, 64]
    const float* U_iuo  = (const float*)d_in[6];  // [64, 192]
    float* out = (float*)d_out;
    float* ws  = (float*)d_ws;

    const size_t R = (size_t)(NN + 1) * 64;
    float* h0 = ws;
    float* c0 = ws + R;
    float* h1 = ws + 2 * R;
    float* c1 = ws + 3 * R;
    float* gb = ws + 4 * R;                        // single g buffer (write-after-consume)
    float* Wx = ws + 5 * R;                        // [N, 256]; f-slot reused for branch_f
    float* hs = Wx + (size_t)NN * 256;             // [N, 64]

    float* hp = h0; float* cp = c0;
    float* hn = h1; float* cn = c1;
    for (int d = 0; d < DD; ++d) {
        const int last = (d == DD - 1);
        k0_wx<<<2048, 256, 0, stream>>>(labels + (size_t)d * NN, E, W_w, W_b, Wx);
        k1_child<<<NN / 4, 256, 0, stream>>>(child + (size_t)d * NN * KK, hp, cp, gb,
                                             Wx, hs, d == 0);
        k2_out<<<2048, 256, 0, stream>>>(hs, Wx, U_iuo, hn, cn, out, last);
        if (!last) kg_gf<<<2048, 256, 0, stream>>>(hn, U_f, gb);
        float* th = hp; hp = hn; hn = th;
        float* tc = cp; cp = cn; cn = tc;
    }
}

// Round 3
// 907.315 us; speedup vs baseline: 1.3929x; 1.0177x over previous
//
#include <hip/hip_runtime.h>

#define NN 32768
#define KK 16
#define DD 6

// Interleaved state row layout, per node j (row stride 192 floats = 768 B):
//   [ h(64) | c(64) | g(64) ]   where g = h @ U_f (precomputed once per depth)
#define SROW 192

__device__ __forceinline__ float sigm(float x) { return 1.0f / (1.0f + __expf(-x)); }
__device__ __forceinline__ float ftanh(float x) {
    float e = __expf(2.0f * x);
    return 1.0f - 2.0f / (e + 1.0f);
}

// K0: Wx[n, 0:256] = E[labels[n]] @ W_w + W_b
// wave g = gate g; W_w column resident in 64 VGPRs (waves_per_eu(4,4) pins the
// allocator budget at 128 VGPRs -- launch_bounds' 2nd arg alone did NOT stop
// the spill in R1: VGPR_Count was 36). x row wave-uniform -> s_load chain.
__global__ __launch_bounds__(256) __attribute__((amdgpu_waves_per_eu(4, 4)))
void k0_wx(const int* __restrict__ labels, const float* __restrict__ E,
           const float* __restrict__ W_w, const float* __restrict__ W_b,
           float* __restrict__ Wx)
{
    const int t = threadIdx.x & 63;
    const int g = __builtin_amdgcn_readfirstlane((int)(threadIdx.x >> 6));
    float w[64];
#pragma unroll
    for (int d = 0; d < 64; ++d) w[d] = W_w[d * 256 + g * 64 + t];
    const float b = W_b[g * 64 + t];
    for (int n = blockIdx.x; n < NN; n += gridDim.x) {
        const int lab = labels[n];                           // uniform
        const float* __restrict__ x = E + (size_t)lab * 64;  // uniform row -> s_load
        float a0 = b, a1 = 0.f, a2 = 0.f, a3 = 0.f;
#pragma unroll
        for (int d = 0; d < 64; d += 4) {
            a0 = fmaf(x[d + 0], w[d + 0], a0);
            a1 = fmaf(x[d + 1], w[d + 1], a1);
            a2 = fmaf(x[d + 2], w[d + 2], a2);
            a3 = fmaf(x[d + 3], w[d + 3], a3);
        }
        Wx[(size_t)n * 256 + g * 64 + t] = (a0 + a1) + (a2 + a3);
    }
}

// K1: pure gather. One wave per node. All 48 loads issued before any use
// (128-VGPR budget => real MLP, R1 had VGPR=24 and ~8 in flight).
// Rows 0 of the state are zero => idx==0 (mask) is free.
// h_sum staged into the g-slot of the NEXT-state buffer (kg overwrites later);
// branch_f overwrites the consumed Wf_x slot of Wx.
__global__ __launch_bounds__(256) __attribute__((amdgpu_waves_per_eu(4, 4)))
void k1_child(const int* __restrict__ cidx, const float* __restrict__ sprev,
              float* __restrict__ Wx, float* __restrict__ snext, int first)
{
    const int t = threadIdx.x & 63;
    const int w = __builtin_amdgcn_readfirstlane((int)(threadIdx.x >> 6));
    const int n = blockIdx.x * 4 + w;
    float hs = 0.f, bf = 0.f;
    if (!first) {
        const int* __restrict__ ci = cidx + (size_t)n * KK;
        int j[KK];
#pragma unroll
        for (int k = 0; k < KK; ++k) j[k] = ci[k] * SROW + t;  // uniform*SROW + lane
        float hv[KK], cv[KK], gv[KK];
#pragma unroll
        for (int k = 0; k < KK; ++k) hv[k] = sprev[j[k]];
#pragma unroll
        for (int k = 0; k < KK; ++k) cv[k] = sprev[j[k] + 64];
#pragma unroll
        for (int k = 0; k < KK; ++k) gv[k] = sprev[j[k] + 128];
        const float wfx = Wx[(size_t)n * 256 + t];
        float h0 = 0.f, h1 = 0.f, h2 = 0.f, h3 = 0.f;
#pragma unroll
        for (int k = 0; k < KK; k += 4) {
            h0 += hv[k]; h1 += hv[k + 1]; h2 += hv[k + 2]; h3 += hv[k + 3];
            bf = fmaf(sigm(wfx + gv[k]), cv[k], bf);
            bf = fmaf(sigm(wfx + gv[k + 1]), cv[k + 1], bf);
            bf = fmaf(sigm(wfx + gv[k + 2]), cv[k + 2], bf);
            bf = fmaf(sigm(wfx + gv[k + 3]), cv[k + 3], bf);
        }
        hs = (h0 + h1) + (h2 + h3);
    }
    snext[(size_t)(n + 1) * SROW + 128 + t] = hs;  // h_sum -> g-slot (temp)
    Wx[(size_t)n * 256 + t] = bf;                  // branch_f -> f-slot
}

// K2: iuo = h_sum @ U_iuo; gates; new_c = i*u + bf; new_h = o*tanh(new_c).
// 192 weight VGPRs resident (waves_per_eu(2,2) => 256-VGPR budget).
__global__ __launch_bounds__(256) __attribute__((amdgpu_waves_per_eu(2, 2)))
void k2_out(const float* __restrict__ Wx, const float* __restrict__ U_iuo,
            float* __restrict__ snext, float* __restrict__ out, int last)
{
    const int t = threadIdx.x & 63;
    const int w = __builtin_amdgcn_readfirstlane((int)(threadIdx.x >> 6));
    float ui[64], uu[64], uo[64];
#pragma unroll
    for (int d = 0; d < 64; ++d) {
        ui[d] = U_iuo[d * 192 + t];
        uu[d] = U_iuo[d * 192 + 64 + t];
        uo[d] = U_iuo[d * 192 + 128 + t];
    }
    const int nw = gridDim.x * 4;
    for (int n = blockIdx.x * 4 + w; n < NN; n += nw) {
        const float* __restrict__ hr = snext + (size_t)(n + 1) * SROW + 128;  // uniform
        float ai = Wx[(size_t)n * 256 + 64 + t];
        float au = Wx[(size_t)n * 256 + 128 + t];
        float ao = Wx[(size_t)n * 256 + 192 + t];
#pragma unroll
        for (int d = 0; d < 64; ++d) {
            const float hv = hr[d];                           // s_load
            ai = fmaf(hv, ui[d], ai);
            au = fmaf(hv, uu[d], au);
            ao = fmaf(hv, uo[d], ao);
        }
        const float ig = sigm(ai);
        const float ug = ftanh(au);
        const float og = sigm(ao);
        const float nc = fmaf(ig, ug, Wx[(size_t)n * 256 + t]);  // bf from f-slot
        const float nh = og * ftanh(nc);
        if (last) {
            out[(size_t)n * 64 + t] = nh;
        } else {
            snext[(size_t)(n + 1) * SROW + t] = nh;
            snext[(size_t)(n + 1) * SROW + 64 + t] = nc;
        }
    }
    if (!last && blockIdx.x == 0 && threadIdx.x < 64) {
        snext[threadIdx.x] = 0.f;        // zero row 0 h
        snext[64 + threadIdx.x] = 0.f;   // zero row 0 c
    }
}

// Kg: g-slot[n] = h[n] @ U_f (factored per-child matvec, once per row).
// Overwrites the h_sum staging in the g-slot AFTER k2 consumed it.
__global__ __launch_bounds__(256) __attribute__((amdgpu_waves_per_eu(4, 4)))
void kg_gf(float* __restrict__ snext, const float* __restrict__ U_f)
{
    const int t = threadIdx.x & 63;
    const int w = __builtin_amdgcn_readfirstlane((int)(threadIdx.x >> 6));
    float uf[64];
#pragma unroll
    for (int d = 0; d < 64; ++d) uf[d] = U_f[d * 64 + t];
    const int nw = gridDim.x * 4;
    for (int n = blockIdx.x * 4 + w; n < NN; n += nw) {
        const float* __restrict__ hr = snext + (size_t)(n + 1) * SROW;  // uniform row
        float a0 = 0.f, a1 = 0.f, a2 = 0.f, a3 = 0.f;
#pragma unroll
        for (int d = 0; d < 64; d += 4) {
            a0 = fmaf(hr[d + 0], uf[d + 0], a0);
            a1 = fmaf(hr[d + 1], uf[d + 1], a1);
            a2 = fmaf(hr[d + 2], uf[d + 2], a2);
            a3 = fmaf(hr[d + 3], uf[d + 3], a3);
        }
        snext[(size_t)(n + 1) * SROW + 128 + t] = (a0 + a1) + (a2 + a3);
    }
    if (blockIdx.x == 0 && threadIdx.x < 64)
        snext[128 + threadIdx.x] = 0.f;  // zero row 0 g
}

extern "C" void kernel_launch(void* const* d_in, const int* in_sizes, int n_in,
                              void* d_out, int out_size, void* d_ws, size_t ws_size,
                              hipStream_t stream)
{
    const int*   labels = (const int*)d_in[0];    // [6, 32768]
    const int*   child  = (const int*)d_in[1];    // [6, 32768, 16]
    const float* E      = (const float*)d_in[2];  // [100000, 64]
    const float* W_w    = (const float*)d_in[3];  // [64, 256]
    const float* W_b    = (const float*)d_in[4];  // [256]
    const float* U_f    = (const float*)d_in[5];  // [64, 64]
    const float* U_iuo  = (const float*)d_in[6];  // [64, 192]
    float* out = (float*)d_out;
    float* ws  = (float*)d_ws;

    const size_t R = (size_t)(NN + 1) * SROW;     // interleaved state rows
    float* s0 = ws;                               // state buffer A
    float* s1 = ws + R;                           // state buffer B
    float* Wx = ws + 2 * R;                       // [N, 256]; f-slot reused for branch_f
    // total: 2*R + N*256 = ~12.6M + 8.4M floats = ~84 MB

    float* sp = s0;
    float* sn = s1;
    for (int d = 0; d < DD; ++d) {
        const int last = (d == DD - 1);
        k0_wx<<<4096, 256, 0, stream>>>(labels + (size_t)d * NN, E, W_w, W_b, Wx);
        k1_child<<<NN / 4, 256, 0, stream>>>(child + (size_t)d * NN * KK, sp, Wx, sn,
                                             d == 0);
        k2_out<<<1024, 256, 0, stream>>>(Wx, U_iuo, sn, out, last);
        if (!last) kg_gf<<<2048, 256, 0, stream>>>(sn, U_f);
        float* ts = sp; sp = sn; sn = ts;
    }
}

// Round 4
// 539.291 us; speedup vs baseline: 2.3434x; 1.6824x over previous
//
#include <hip/hip_runtime.h>

#define NN 32768
#define KK 16
#define DD 6
// Interleaved state row per node j (stride 192 floats): [ h(64) | c(64) | g(64) ]
#define SROW 192

typedef short short8 __attribute__((ext_vector_type(8)));
typedef float floatx4 __attribute__((ext_vector_type(4)));

__device__ __forceinline__ float sigm(float x) { return 1.0f / (1.0f + __expf(-x)); }
__device__ __forceinline__ float ftanh(float x) {
    float e = __expf(2.0f * x);
    return 1.0f - 2.0f / (e + 1.0f);
}
__device__ __forceinline__ unsigned short f2bf(float x) {   // RNE fp32->bf16
    union { float f; unsigned u; } v; v.f = x;
    unsigned r = v.u + 0x7FFF + ((v.u >> 16) & 1);
    return (unsigned short)(r >> 16);
}
__device__ __forceinline__ float bf2f(unsigned short h) {
    union { unsigned u; float f; } v; v.u = ((unsigned)h) << 16; return v.f;
}

// ---------------------------------------------------------------------------
// K0 (MFMA): Wx[n,0:256] = E[labels[n]] @ W_w + W_b    (bf16 in, fp32 acc)
// Block = 64 nodes. Wave wv owns m-tile wv (16 nodes) x all 256 cols.
// LDS 46KB caps occupancy at 3 blocks/CU -> allocator VGPR budget ~170,
// and MFMA accs are structurally un-sinkable: no more residency fights.
// A err ~3e-5 on Wx (tiny operands) -> plain bf16 is safe here.
__global__ __launch_bounds__(256) void k0_mfma(
    const int* __restrict__ labels, const float* __restrict__ E,
    const float* __restrict__ W_w, const float* __restrict__ W_b,
    float* __restrict__ Wx)
{
    __shared__ int labs[64];
    __shared__ __align__(16) unsigned short Ax[64][72];    // x rows, bf16, +16B pad
    __shared__ __align__(16) unsigned short Bw[256][72];   // W_w^T [col][k], bf16
    const int tid = threadIdx.x;
    const int n0 = blockIdx.x * 64;
    if (tid < 64) labs[tid] = labels[n0 + tid];
    __syncthreads();
    {   // stage A: thread -> node m = tid>>2, 16 dims
        const int m = tid >> 2, q = tid & 3;
        const float4* e4 = (const float4*)(E + (size_t)labs[m] * 64 + q * 16);
#pragma unroll
        for (int i = 0; i < 4; ++i) {
            float4 v = e4[i];
            Ax[m][q * 16 + i * 4 + 0] = f2bf(v.x);
            Ax[m][q * 16 + i * 4 + 1] = f2bf(v.y);
            Ax[m][q * 16 + i * 4 + 2] = f2bf(v.z);
            Ax[m][q * 16 + i * 4 + 3] = f2bf(v.w);
        }
    }
    {   // stage B transposed: thread = col, coalesced global reads per k
        const int c = tid;
#pragma unroll 4
        for (int k = 0; k < 64; ++k) Bw[c][k] = f2bf(W_w[k * 256 + c]);
    }
    __syncthreads();
    const int ln = tid & 63, wv = tid >> 6;
    const int lr = ln & 15, qd = ln >> 4;
    short8 af[2];
#pragma unroll
    for (int ks = 0; ks < 2; ++ks)
        af[ks] = *(const short8*)&Ax[wv * 16 + lr][ks * 32 + qd * 8];
    floatx4 acc[16];
#pragma unroll
    for (int nt = 0; nt < 16; ++nt) acc[nt] = (floatx4){0.f, 0.f, 0.f, 0.f};
#pragma unroll
    for (int nt = 0; nt < 16; ++nt) {
#pragma unroll
        for (int ks = 0; ks < 2; ++ks) {
            short8 bw = *(const short8*)&Bw[nt * 16 + lr][ks * 32 + qd * 8];
            acc[nt] = __builtin_amdgcn_mfma_f32_16x16x32_bf16(af[ks], bw, acc[nt], 0, 0, 0);
        }
    }
    // C/D layout (gfx950, m89-verified): col = lane&15, row = quad*4 + reg
#pragma unroll
    for (int nt = 0; nt < 16; ++nt) {
        const int col = nt * 16 + lr;
        const float bb = W_b[col];
#pragma unroll
        for (int r = 0; r < 4; ++r) {
            const int node = n0 + wv * 16 + qd * 4 + r;
            Wx[(size_t)node * 256 + col] = acc[nt][r] + bb;
        }
    }
}

// ---------------------------------------------------------------------------
// K1 (unchanged from R3): pure gather. hs -> snext g-slot; bf -> Wx f-slot.
__global__ __launch_bounds__(256) __attribute__((amdgpu_waves_per_eu(4, 4)))
void k1_child(const int* __restrict__ cidx, const float* __restrict__ sprev,
              float* __restrict__ Wx, float* __restrict__ snext, int first)
{
    const int t = threadIdx.x & 63;
    const int w = __builtin_amdgcn_readfirstlane((int)(threadIdx.x >> 6));
    const int n = blockIdx.x * 4 + w;
    float hs = 0.f, bf = 0.f;
    if (!first) {
        const int* __restrict__ ci = cidx + (size_t)n * KK;
        int j[KK];
#pragma unroll
        for (int k = 0; k < KK; ++k) j[k] = ci[k] * SROW + t;
        float hv[KK], cv[KK], gv[KK];
#pragma unroll
        for (int k = 0; k < KK; ++k) hv[k] = sprev[j[k]];
#pragma unroll
        for (int k = 0; k < KK; ++k) cv[k] = sprev[j[k] + 64];
#pragma unroll
        for (int k = 0; k < KK; ++k) gv[k] = sprev[j[k] + 128];
        const float wfx = Wx[(size_t)n * 256 + t];
        float h0 = 0.f, h1 = 0.f, h2 = 0.f, h3 = 0.f;
#pragma unroll
        for (int k = 0; k < KK; k += 4) {
            h0 += hv[k]; h1 += hv[k + 1]; h2 += hv[k + 2]; h3 += hv[k + 3];
            bf = fmaf(sigm(wfx + gv[k]), cv[k], bf);
            bf = fmaf(sigm(wfx + gv[k + 1]), cv[k + 1], bf);
            bf = fmaf(sigm(wfx + gv[k + 2]), cv[k + 2], bf);
            bf = fmaf(sigm(wfx + gv[k + 3]), cv[k + 3], bf);
        }
        hs = (h0 + h1) + (h2 + h3);
    }
    snext[(size_t)(n + 1) * SROW + 128 + t] = hs;  // h_sum -> g-slot (temp)
    Wx[(size_t)n * 256 + t] = bf;                  // branch_f -> f-slot
}

// ---------------------------------------------------------------------------
// K2G (MFMA, fused k2+kg): iuo = hsum @ U_iuo (split-bf16 A: |hsum|<=16 is the
// precision-critical operand); gates+pointwise epilogue in C-layout registers;
// then g = nh @ U_f via in-kernel restage of nh to A-layout LDS (per-wave tile,
// no barrier needed). Writes h,c,g interleaved; block 0 zeroes row 0.
// LDS ~64.5KB -> 2 blocks/CU -> VGPR budget 256: accs safe.
__global__ __launch_bounds__(256) void k2g_mfma(
    const float* __restrict__ Wx, const float* __restrict__ U_iuo,
    const float* __restrict__ U_f, float* __restrict__ snext,
    float* __restrict__ out, int last)
{
    __shared__ __align__(16) unsigned short Bi[192][72];  // U_iuo^T [c][k]
    __shared__ __align__(16) unsigned short Bf[64][72];   // U_f^T   [c][k]
    __shared__ __align__(16) unsigned short Ah[64][72];   // hsum hi
    __shared__ __align__(16) unsigned short Al[64][72];   // hsum lo
    __shared__ __align__(16) unsigned short Hs[64][72];   // nh bf16 (per-wave tiles)
    const int tid = threadIdx.x;
    const int n0 = blockIdx.x * 64;
    if (tid < 192) {
        const int c = tid;
#pragma unroll 4
        for (int k = 0; k < 64; ++k) Bi[c][k] = f2bf(U_iuo[k * 192 + c]);
    } else {
        const int c = tid - 192;
#pragma unroll 4
        for (int k = 0; k < 64; ++k) Bf[c][k] = f2bf(U_f[k * 64 + c]);
    }
    {   // stage A (hsum from snext g-slot), split hi/lo bf16
        const int m = tid >> 2, q = tid & 3;
        const float4* h4 = (const float4*)(snext + (size_t)(n0 + m + 1) * SROW + 128 + q * 16);
#pragma unroll
        for (int i = 0; i < 4; ++i) {
            float4 v = h4[i];
            float xs[4] = {v.x, v.y, v.z, v.w};
#pragma unroll
            for (int jj = 0; jj < 4; ++jj) {
                unsigned short hi = f2bf(xs[jj]);
                Ah[m][q * 16 + i * 4 + jj] = hi;
                Al[m][q * 16 + i * 4 + jj] = f2bf(xs[jj] - bf2f(hi));
            }
        }
    }
    __syncthreads();
    const int ln = tid & 63, wv = tid >> 6;
    const int lr = ln & 15, qd = ln >> 4;
    short8 ah[2], al[2];
#pragma unroll
    for (int ks = 0; ks < 2; ++ks) {
        ah[ks] = *(const short8*)&Ah[wv * 16 + lr][ks * 32 + qd * 8];
        al[ks] = *(const short8*)&Al[wv * 16 + lr][ks * 32 + qd * 8];
    }
    floatx4 ai[4], au[4], ao[4];
#pragma unroll
    for (int nt = 0; nt < 4; ++nt) {
        ai[nt] = (floatx4){0.f, 0.f, 0.f, 0.f};
        au[nt] = (floatx4){0.f, 0.f, 0.f, 0.f};
        ao[nt] = (floatx4){0.f, 0.f, 0.f, 0.f};
    }
#pragma unroll
    for (int nt = 0; nt < 4; ++nt) {
#pragma unroll
        for (int ks = 0; ks < 2; ++ks) {
            short8 b0 = *(const short8*)&Bi[nt * 16 + lr][ks * 32 + qd * 8];
            short8 b1 = *(const short8*)&Bi[64 + nt * 16 + lr][ks * 32 + qd * 8];
            short8 b2 = *(const short8*)&Bi[128 + nt * 16 + lr][ks * 32 + qd * 8];
            ai[nt] = __builtin_amdgcn_mfma_f32_16x16x32_bf16(al[ks], b0, ai[nt], 0, 0, 0);
            ai[nt] = __builtin_amdgcn_mfma_f32_16x16x32_bf16(ah[ks], b0, ai[nt], 0, 0, 0);
            au[nt] = __builtin_amdgcn_mfma_f32_16x16x32_bf16(al[ks], b1, au[nt], 0, 0, 0);
            au[nt] = __builtin_amdgcn_mfma_f32_16x16x32_bf16(ah[ks], b1, au[nt], 0, 0, 0);
            ao[nt] = __builtin_amdgcn_mfma_f32_16x16x32_bf16(al[ks], b2, ao[nt], 0, 0, 0);
            ao[nt] = __builtin_amdgcn_mfma_f32_16x16x32_bf16(ah[ks], b2, ao[nt], 0, 0, 0);
        }
    }
    // epilogue in C-layout: node = n0 + wv*16 + qd*4 + r, col = nt*16 + lr
#pragma unroll
    for (int nt = 0; nt < 4; ++nt) {
        const int col = nt * 16 + lr;
#pragma unroll
        for (int r = 0; r < 4; ++r) {
            const int node = n0 + wv * 16 + qd * 4 + r;
            const float* __restrict__ wxr = Wx + (size_t)node * 256;
            const float bfv = wxr[col];                       // branch_f (from k1)
            const float ig = sigm(ai[nt][r] + wxr[64 + col]);
            const float ug = ftanh(au[nt][r] + wxr[128 + col]);
            const float og = sigm(ao[nt][r] + wxr[192 + col]);
            const float nc = fmaf(ig, ug, bfv);
            const float nh = og * ftanh(nc);
            if (last) {
                out[(size_t)node * 64 + col] = nh;
            } else {
                snext[(size_t)(node + 1) * SROW + col] = nh;
                snext[(size_t)(node + 1) * SROW + 64 + col] = nc;
                Hs[wv * 16 + qd * 4 + r][col] = f2bf(nh);  // restage for g-GEMM
            }
        }
    }
    if (!last) {
        // g = nh @ U_f ; Hs tile is wave-private (rows wv*16..+15): no barrier,
        // compiler inserts the lgkmcnt wait for the ds write->read dependency.
        short8 ag[2];
#pragma unroll
        for (int ks = 0; ks < 2; ++ks)
            ag[ks] = *(const short8*)&Hs[wv * 16 + lr][ks * 32 + qd * 8];
        floatx4 g[4];
#pragma unroll
        for (int nt = 0; nt < 4; ++nt) g[nt] = (floatx4){0.f, 0.f, 0.f, 0.f};
#pragma unroll
        for (int nt = 0; nt < 4; ++nt) {
#pragma unroll
            for (int ks = 0; ks < 2; ++ks) {
                short8 bfr = *(const short8*)&Bf[nt * 16 + lr][ks * 32 + qd * 8];
                g[nt] = __builtin_amdgcn_mfma_f32_16x16x32_bf16(ag[ks], bfr, g[nt], 0, 0, 0);
            }
        }
#pragma unroll
        for (int nt = 0; nt < 4; ++nt) {
#pragma unroll
            for (int r = 0; r < 4; ++r) {
                const int node = n0 + wv * 16 + qd * 4 + r;
                snext[(size_t)(node + 1) * SROW + 128 + nt * 16 + lr] = g[nt][r];
            }
        }
        if (blockIdx.x == 0 && tid < SROW) snext[tid] = 0.f;  // zero init-state row
    }
}

extern "C" void kernel_launch(void* const* d_in, const int* in_sizes, int n_in,
                              void* d_out, int out_size, void* d_ws, size_t ws_size,
                              hipStream_t stream)
{
    const int*   labels = (const int*)d_in[0];    // [6, 32768]
    const int*   child  = (const int*)d_in[1];    // [6, 32768, 16]
    const float* E      = (const float*)d_in[2];  // [100000, 64]
    const float* W_w    = (const float*)d_in[3];  // [64, 256]
    const float* W_b    = (const float*)d_in[4];  // [256]
    const float* U_f    = (const float*)d_in[5];  // [64, 64]
    const float* U_iuo  = (const float*)d_in[6];  // [64, 192]
    float* out = (float*)d_out;
    float* ws  = (float*)d_ws;

    const size_t R = (size_t)(NN + 1) * SROW;
    float* s0 = ws;
    float* s1 = ws + R;
    float* Wx = ws + 2 * R;                       // [N,256]; f-slot reused for branch_f

    float* sp = s0;
    float* sn = s1;
    for (int d = 0; d < DD; ++d) {
        const int last = (d == DD - 1);
        k0_mfma<<<NN / 64, 256, 0, stream>>>(labels + (size_t)d * NN, E, W_w, W_b, Wx);
        k1_child<<<NN / 4, 256, 0, stream>>>(child + (size_t)d * NN * KK, sp, Wx, sn,
                                             d == 0);
        k2g_mfma<<<NN / 64, 256, 0, stream>>>(Wx, U_iuo, U_f, sn, out, last);
        float* ts = sp; sp = sn; sn = ts;
    }
}

// Round 5
// 439.059 us; speedup vs baseline: 2.8784x; 1.2283x over previous
//
#include <hip/hip_runtime.h>

#define NN 32768
#define KK 16
#define DD 6
// State row per node-slot j (512 B = 128 words):
//   words [0..64):  u32 pack = (int16)(h*32767) | (int16)(g*2048) << 16
//   words [64..128): c as fp32
// Row 0 = all zero (child_idx==0 masking is free).
#define SW 128

typedef short short8 __attribute__((ext_vector_type(8)));
typedef float floatx4 __attribute__((ext_vector_type(4)));

__device__ __forceinline__ float sigm(float x) { return 1.0f / (1.0f + __expf(-x)); }
__device__ __forceinline__ float ftanh(float x) {
    float e = __expf(2.0f * x);
    return 1.0f - 2.0f / (e + 1.0f);
}
__device__ __forceinline__ unsigned short f2bf(float x) {   // RNE fp32->bf16
    union { float f; unsigned u; } v; v.f = x;
    unsigned r = v.u + 0x7FFF + ((v.u >> 16) & 1);
    return (unsigned short)(r >> 16);
}
__device__ __forceinline__ float bf2f(unsigned short h) {
    union { unsigned u; float f; } v; v.u = ((unsigned)h) << 16; return v.f;
}

// ---------------------------------------------------------------------------
// K0 (MFMA): Wx[n,0:256] = E[labels[n]] @ W_w + W_b  (unchanged from R4)
__global__ __launch_bounds__(256) void k0_mfma(
    const int* __restrict__ labels, const float* __restrict__ E,
    const float* __restrict__ W_w, const float* __restrict__ W_b,
    float* __restrict__ Wx)
{
    __shared__ int labs[64];
    __shared__ __align__(16) unsigned short Ax[64][72];
    __shared__ __align__(16) unsigned short Bw[256][72];
    const int tid = threadIdx.x;
    const int n0 = blockIdx.x * 64;
    if (tid < 64) labs[tid] = labels[n0 + tid];
    __syncthreads();
    {
        const int m = tid >> 2, q = tid & 3;
        const float4* e4 = (const float4*)(E + (size_t)labs[m] * 64 + q * 16);
#pragma unroll
        for (int i = 0; i < 4; ++i) {
            float4 v = e4[i];
            Ax[m][q * 16 + i * 4 + 0] = f2bf(v.x);
            Ax[m][q * 16 + i * 4 + 1] = f2bf(v.y);
            Ax[m][q * 16 + i * 4 + 2] = f2bf(v.z);
            Ax[m][q * 16 + i * 4 + 3] = f2bf(v.w);
        }
    }
    {
        const int c = tid;
#pragma unroll 4
        for (int k = 0; k < 64; ++k) Bw[c][k] = f2bf(W_w[k * 256 + c]);
    }
    __syncthreads();
    const int ln = tid & 63, wv = tid >> 6;
    const int lr = ln & 15, qd = ln >> 4;
    short8 af[2];
#pragma unroll
    for (int ks = 0; ks < 2; ++ks)
        af[ks] = *(const short8*)&Ax[wv * 16 + lr][ks * 32 + qd * 8];
    floatx4 acc[16];
#pragma unroll
    for (int nt = 0; nt < 16; ++nt) acc[nt] = (floatx4){0.f, 0.f, 0.f, 0.f};
#pragma unroll
    for (int nt = 0; nt < 16; ++nt) {
#pragma unroll
        for (int ks = 0; ks < 2; ++ks) {
            short8 bw = *(const short8*)&Bw[nt * 16 + lr][ks * 32 + qd * 8];
            acc[nt] = __builtin_amdgcn_mfma_f32_16x16x32_bf16(af[ks], bw, acc[nt], 0, 0, 0);
        }
    }
#pragma unroll
    for (int nt = 0; nt < 16; ++nt) {
        const int col = nt * 16 + lr;
        const float bb = W_b[col];
#pragma unroll
        for (int r = 0; r < 4; ++r) {
            const int node = n0 + wv * 16 + qd * 4 + r;
            Wx[(size_t)node * 256 + col] = acc[nt][r] + bb;
        }
    }
}

// ---------------------------------------------------------------------------
// K1: gather, 2 loads/child (u32 hg-pack + f32 c), 512 B/child total.
// At the random-gather fabric BW limit -> time scales with bytes (R4 analysis).
// h_sum (fp32) staged into snext hg-slot; branch_f -> Wx f-slot.
__global__ __launch_bounds__(256)
void k1_child(const int* __restrict__ cidx, const float* __restrict__ sprev,
              float* __restrict__ Wx, float* __restrict__ snext, int first)
{
    const int t = threadIdx.x & 63;
    const int w = __builtin_amdgcn_readfirstlane((int)(threadIdx.x >> 6));
    const int n = blockIdx.x * 4 + w;
    float hs = 0.f, bf = 0.f;
    if (!first) {
        const int* __restrict__ ci = cidx + (size_t)n * KK;
        int j[KK];
#pragma unroll
        for (int k = 0; k < KK; ++k) j[k] = ci[k] * SW + t;   // uniform*SW + lane
        const unsigned* __restrict__ su = (const unsigned*)sprev;
        unsigned hg[KK];
        float cv[KK];
#pragma unroll
        for (int k = 0; k < KK; ++k) hg[k] = su[j[k]];
#pragma unroll
        for (int k = 0; k < KK; ++k) cv[k] = sprev[j[k] + 64];
        const float wfx = Wx[(size_t)n * 256 + t];
        float h0 = 0.f, h1 = 0.f;
#pragma unroll
        for (int k = 0; k < KK; k += 2) {
            const int hq0 = (int)(short)(hg[k] & 0xFFFFu);
            const int gq0 = ((int)hg[k]) >> 16;
            const int hq1 = (int)(short)(hg[k + 1] & 0xFFFFu);
            const int gq1 = ((int)hg[k + 1]) >> 16;
            h0 = fmaf((float)hq0, 1.f / 32767.f, h0);
            h1 = fmaf((float)hq1, 1.f / 32767.f, h1);
            bf = fmaf(sigm(fmaf((float)gq0, 1.f / 2048.f, wfx)), cv[k], bf);
            bf = fmaf(sigm(fmaf((float)gq1, 1.f / 2048.f, wfx)), cv[k + 1], bf);
        }
        hs = h0 + h1;
    }
    ((float*)snext)[(size_t)(n + 1) * SW + t] = hs;   // h_sum -> hg-slot (fp32 temp)
    Wx[(size_t)n * 256 + t] = bf;                     // branch_f -> f-slot
}

// ---------------------------------------------------------------------------
// K2G (MFMA): iuo = hsum @ U_iuo (split-bf16 A); gate epilogue; g = nh @ U_f
// via per-wave LDS restage; h+g packed int16 + c fp32 stored interleaved.
__global__ __launch_bounds__(256) void k2g_mfma(
    const float* __restrict__ Wx, const float* __restrict__ U_iuo,
    const float* __restrict__ U_f, float* __restrict__ snext,
    float* __restrict__ out, int last)
{
    __shared__ __align__(16) unsigned short Bi[192][72];  // U_iuo^T [c][k]
    __shared__ __align__(16) unsigned short Bf[64][72];   // U_f^T   [c][k]
    __shared__ __align__(16) unsigned short Ah[64][72];   // hsum hi
    __shared__ __align__(16) unsigned short Al[64][72];   // hsum lo
    __shared__ __align__(16) unsigned short Hs[64][72];   // nh bf16 (per-wave tiles)
    const int tid = threadIdx.x;
    const int n0 = blockIdx.x * 64;
    if (tid < 192) {
        const int c = tid;
#pragma unroll 4
        for (int k = 0; k < 64; ++k) Bi[c][k] = f2bf(U_iuo[k * 192 + c]);
    } else {
        const int c = tid - 192;
#pragma unroll 4
        for (int k = 0; k < 64; ++k) Bf[c][k] = f2bf(U_f[k * 64 + c]);
    }
    {   // stage A: hsum (fp32, staged by k1 in hg-slot), split hi/lo bf16
        const int m = tid >> 2, q = tid & 3;
        const float4* h4 = (const float4*)(snext + (size_t)(n0 + m + 1) * SW + q * 16);
#pragma unroll
        for (int i = 0; i < 4; ++i) {
            float4 v = h4[i];
            float xs[4] = {v.x, v.y, v.z, v.w};
#pragma unroll
            for (int jj = 0; jj < 4; ++jj) {
                unsigned short hi = f2bf(xs[jj]);
                Ah[m][q * 16 + i * 4 + jj] = hi;
                Al[m][q * 16 + i * 4 + jj] = f2bf(xs[jj] - bf2f(hi));
            }
        }
    }
    __syncthreads();
    const int ln = tid & 63, wv = tid >> 6;
    const int lr = ln & 15, qd = ln >> 4;
    short8 ah[2], al[2];
#pragma unroll
    for (int ks = 0; ks < 2; ++ks) {
        ah[ks] = *(const short8*)&Ah[wv * 16 + lr][ks * 32 + qd * 8];
        al[ks] = *(const short8*)&Al[wv * 16 + lr][ks * 32 + qd * 8];
    }
    floatx4 ai[4], au[4], ao[4];
#pragma unroll
    for (int nt = 0; nt < 4; ++nt) {
        ai[nt] = (floatx4){0.f, 0.f, 0.f, 0.f};
        au[nt] = (floatx4){0.f, 0.f, 0.f, 0.f};
        ao[nt] = (floatx4){0.f, 0.f, 0.f, 0.f};
    }
#pragma unroll
    for (int nt = 0; nt < 4; ++nt) {
#pragma unroll
        for (int ks = 0; ks < 2; ++ks) {
            short8 b0 = *(const short8*)&Bi[nt * 16 + lr][ks * 32 + qd * 8];
            short8 b1 = *(const short8*)&Bi[64 + nt * 16 + lr][ks * 32 + qd * 8];
            short8 b2 = *(const short8*)&Bi[128 + nt * 16 + lr][ks * 32 + qd * 8];
            ai[nt] = __builtin_amdgcn_mfma_f32_16x16x32_bf16(al[ks], b0, ai[nt], 0, 0, 0);
            ai[nt] = __builtin_amdgcn_mfma_f32_16x16x32_bf16(ah[ks], b0, ai[nt], 0, 0, 0);
            au[nt] = __builtin_amdgcn_mfma_f32_16x16x32_bf16(al[ks], b1, au[nt], 0, 0, 0);
            au[nt] = __builtin_amdgcn_mfma_f32_16x16x32_bf16(ah[ks], b1, au[nt], 0, 0, 0);
            ao[nt] = __builtin_amdgcn_mfma_f32_16x16x32_bf16(al[ks], b2, ao[nt], 0, 0, 0);
            ao[nt] = __builtin_amdgcn_mfma_f32_16x16x32_bf16(ah[ks], b2, ao[nt], 0, 0, 0);
        }
    }
    // gate epilogue in C-layout: node = n0+wv*16+qd*4+r, col = nt*16+lr.
    // Keep nh in registers so h and g can be packed together after the g-GEMM.
    float nhv[4][4];
#pragma unroll
    for (int nt = 0; nt < 4; ++nt) {
        const int col = nt * 16 + lr;
#pragma unroll
        for (int r = 0; r < 4; ++r) {
            const int node = n0 + wv * 16 + qd * 4 + r;
            const float* __restrict__ wxr = Wx + (size_t)node * 256;
            const float bfv = wxr[col];                       // branch_f (from k1)
            const float ig = sigm(ai[nt][r] + wxr[64 + col]);
            const float ug = ftanh(au[nt][r] + wxr[128 + col]);
            const float og = sigm(ao[nt][r] + wxr[192 + col]);
            const float nc = fmaf(ig, ug, bfv);
            const float nh = og * ftanh(nc);
            nhv[nt][r] = nh;
            if (last) {
                out[(size_t)node * 64 + col] = nh;
            } else {
                snext[(size_t)(node + 1) * SW + 64 + col] = nc;  // c slot fp32
                Hs[wv * 16 + qd * 4 + r][col] = f2bf(nh);        // restage for g-GEMM
            }
        }
    }
    if (!last) {
        // g = nh @ U_f ; Hs tile is wave-private: compiler inserts the lgkmcnt
        // wait for the ds write->read dependency, no barrier needed.
        short8 ag[2];
#pragma unroll
        for (int ks = 0; ks < 2; ++ks)
            ag[ks] = *(const short8*)&Hs[wv * 16 + lr][ks * 32 + qd * 8];
        floatx4 g[4];
#pragma unroll
        for (int nt = 0; nt < 4; ++nt) g[nt] = (floatx4){0.f, 0.f, 0.f, 0.f};
#pragma unroll
        for (int nt = 0; nt < 4; ++nt) {
#pragma unroll
            for (int ks = 0; ks < 2; ++ks) {
                short8 bfr = *(const short8*)&Bf[nt * 16 + lr][ks * 32 + qd * 8];
                g[nt] = __builtin_amdgcn_mfma_f32_16x16x32_bf16(ag[ks], bfr, g[nt], 0, 0, 0);
            }
        }
        unsigned* __restrict__ su = (unsigned*)snext;
#pragma unroll
        for (int nt = 0; nt < 4; ++nt) {
#pragma unroll
            for (int r = 0; r < 4; ++r) {
                const int node = n0 + wv * 16 + qd * 4 + r;
                // |nh|<1 (o*tanh), |g|<=8 (sum |h||U_f|) -> int16 scales safe.
                const int hq = (int)rintf(nhv[nt][r] * 32767.f);
                const int gq = (int)rintf(g[nt][r] * 2048.f);
                const unsigned pw = ((unsigned)hq & 0xFFFFu) | ((unsigned)gq << 16);
                su[(size_t)(node + 1) * SW + nt * 16 + lr] = pw;
            }
        }
        if (blockIdx.x == 0 && tid < SW) snext[tid] = 0.f;  // zero init-state row
    }
}

extern "C" void kernel_launch(void* const* d_in, const int* in_sizes, int n_in,
                              void* d_out, int out_size, void* d_ws, size_t ws_size,
                              hipStream_t stream)
{
    const int*   labels = (const int*)d_in[0];    // [6, 32768]
    const int*   child  = (const int*)d_in[1];    // [6, 32768, 16]
    const float* E      = (const float*)d_in[2];  // [100000, 64]
    const float* W_w    = (const float*)d_in[3];  // [64, 256]
    const float* W_b    = (const float*)d_in[4];  // [256]
    const float* U_f    = (const float*)d_in[5];  // [64, 64]
    const float* U_iuo  = (const float*)d_in[6];  // [64, 192]
    float* out = (float*)d_out;
    float* ws  = (float*)d_ws;

    const size_t R = (size_t)(NN + 1) * SW;       // 512 B state rows
    float* s0 = ws;
    float* s1 = ws + R;
    float* Wx = ws + 2 * R;                       // [N,256]; f-slot reused for branch_f

    float* sp = s0;
    float* sn = s1;
    for (int d = 0; d < DD; ++d) {
        const int last = (d == DD - 1);
        k0_mfma<<<NN / 64, 256, 0, stream>>>(labels + (size_t)d * NN, E, W_w, W_b, Wx);
        k1_child<<<NN / 4, 256, 0, stream>>>(child + (size_t)d * NN * KK, sp, Wx, sn,
                                             d == 0);
        k2g_mfma<<<NN / 64, 256, 0, stream>>>(Wx, U_iuo, U_f, sn, out, last);
        float* ts = sp; sp = sn; sn = ts;
    }
}

// Round 6
// 371.577 us; speedup vs baseline: 3.4011x; 1.1816x over previous
//
#include <hip/hip_runtime.h>

#define NN 32768
#define KK 16
#define DD 6
// State row per node-slot j: 384 B total.
//   u32 words [0..64):   pack = (int16)(h*32767) | (int16)(g*2048)<<16
//   f16 halfwords [128..192) (byte offset 256): c as fp16
// Row 0 = all zero (child_idx==0 masking is free).

typedef short short8 __attribute__((ext_vector_type(8)));
typedef float floatx4 __attribute__((ext_vector_type(4)));

__device__ __forceinline__ float sigm(float x) { return 1.0f / (1.0f + __expf(-x)); }
__device__ __forceinline__ float ftanh(float x) {
    float e = __expf(2.0f * x);
    return 1.0f - 2.0f / (e + 1.0f);
}
__device__ __forceinline__ unsigned short f2bf(float x) {   // RNE fp32->bf16
    union { float f; unsigned u; } v; v.f = x;
    unsigned r = v.u + 0x7FFF + ((v.u >> 16) & 1);
    return (unsigned short)(r >> 16);
}
__device__ __forceinline__ float bf2f(unsigned short h) {
    union { unsigned u; float f; } v; v.u = ((unsigned)h) << 16; return v.f;
}

// ---------------------------------------------------------------------------
// K0_ALL (MFMA): Wx[dep][n,0:256] = E[labels[dep][n]] @ W_w + W_b, all 6 depths
// in ONE launch (depth-independent: only reads labels/E). grid = 6*512 blocks.
__global__ __launch_bounds__(256) void k0_all(
    const int* __restrict__ labels, const float* __restrict__ E,
    const float* __restrict__ W_w, const float* __restrict__ W_b,
    float* __restrict__ WxAll)
{
    __shared__ int labs[64];
    __shared__ __align__(16) unsigned short Ax[64][72];
    __shared__ __align__(16) unsigned short Bw[256][72];
    const int tid = threadIdx.x;
    const int blk = blockIdx.x & 511;
    const int dep = blockIdx.x >> 9;
    const int n0 = blk * 64;
    float* __restrict__ Wx = WxAll + (size_t)dep * NN * 256;
    if (tid < 64) labs[tid] = labels[(size_t)dep * NN + n0 + tid];
    __syncthreads();
    {
        const int m = tid >> 2, q = tid & 3;
        const float4* e4 = (const float4*)(E + (size_t)labs[m] * 64 + q * 16);
#pragma unroll
        for (int i = 0; i < 4; ++i) {
            float4 v = e4[i];
            Ax[m][q * 16 + i * 4 + 0] = f2bf(v.x);
            Ax[m][q * 16 + i * 4 + 1] = f2bf(v.y);
            Ax[m][q * 16 + i * 4 + 2] = f2bf(v.z);
            Ax[m][q * 16 + i * 4 + 3] = f2bf(v.w);
        }
    }
    {
        const int c = tid;
#pragma unroll 4
        for (int k = 0; k < 64; ++k) Bw[c][k] = f2bf(W_w[k * 256 + c]);
    }
    __syncthreads();
    const int ln = tid & 63, wv = tid >> 6;
    const int lr = ln & 15, qd = ln >> 4;
    short8 af[2];
#pragma unroll
    for (int ks = 0; ks < 2; ++ks)
        af[ks] = *(const short8*)&Ax[wv * 16 + lr][ks * 32 + qd * 8];
    floatx4 acc[16];
#pragma unroll
    for (int nt = 0; nt < 16; ++nt) acc[nt] = (floatx4){0.f, 0.f, 0.f, 0.f};
#pragma unroll
    for (int nt = 0; nt < 16; ++nt) {
#pragma unroll
        for (int ks = 0; ks < 2; ++ks) {
            short8 bw = *(const short8*)&Bw[nt * 16 + lr][ks * 32 + qd * 8];
            acc[nt] = __builtin_amdgcn_mfma_f32_16x16x32_bf16(af[ks], bw, acc[nt], 0, 0, 0);
        }
    }
#pragma unroll
    for (int nt = 0; nt < 16; ++nt) {
        const int col = nt * 16 + lr;
        const float bb = W_b[col];
#pragma unroll
        for (int r = 0; r < 4; ++r) {
            const int node = n0 + wv * 16 + qd * 4 + r;
            Wx[(size_t)node * 256 + col] = acc[nt][r] + bb;
        }
    }
}

// ---------------------------------------------------------------------------
// KD (fused gather + iuo-GEMM + gates + g-GEMM + pack-store), one per depth.
// Thread (wv,qd,lr) owns nodes {wv*16+qd*4+r} x cols {nt*16+lr} -- the MFMA
// C-layout -- so branch_f and h_sum never leave registers/LDS.
__global__ __launch_bounds__(256) void kd_fused(
    const int* __restrict__ cidx, const float* __restrict__ sprev,
    const float* __restrict__ Wx, const float* __restrict__ U_iuo,
    const float* __restrict__ U_f, float* __restrict__ snext,
    float* __restrict__ out, int first, int last)
{
    __shared__ __align__(16) unsigned short Bi[192][72];   // U_iuo^T [c][k]
    __shared__ __align__(16) unsigned short Bf[64][72];    // U_f^T   [c][k]
    __shared__ __align__(16) unsigned short Ah[64][72];    // hsum hi
    __shared__ __align__(16) unsigned short AlHs[64][72];  // hsum lo, later nh restage
    const int tid = threadIdx.x;
    const int n0 = blockIdx.x * 64;
    // stage B matrices (bf16, transposed)
    if (tid < 192) {
        const int c = tid;
#pragma unroll 4
        for (int k = 0; k < 64; ++k) Bi[c][k] = f2bf(U_iuo[k * 192 + c]);
    } else {
        const int c = tid - 192;
#pragma unroll 4
        for (int k = 0; k < 64; ++k) Bf[c][k] = f2bf(U_f[k * 64 + c]);
    }
    const int ln = tid & 63, wv = tid >> 6;
    const int lr = ln & 15, qd = ln >> 4;

    // ---- gather phase: hs/bf in C-layout registers
    float hs[4][4] = {{0.f}}, bfv[4][4] = {{0.f}};
    if (!first) {
        float wfx[4][4];
#pragma unroll
        for (int r = 0; r < 4; ++r)
#pragma unroll
            for (int nt = 0; nt < 4; ++nt)
                wfx[r][nt] = Wx[(size_t)(n0 + wv * 16 + qd * 4 + r) * 256 + nt * 16 + lr];
        const unsigned* __restrict__ su = (const unsigned*)sprev;
        const _Float16* __restrict__ chh = (const _Float16*)sprev;
        for (int k = 0; k < KK; ++k) {
            int id[4];
#pragma unroll
            for (int r = 0; r < 4; ++r)
                id[r] = cidx[(size_t)(n0 + wv * 16 + qd * 4 + r) * KK + k];
            unsigned hg[4][4];
            float cc[4][4];
#pragma unroll
            for (int r = 0; r < 4; ++r)
#pragma unroll
                for (int nt = 0; nt < 4; ++nt)
                    hg[r][nt] = su[(size_t)id[r] * 96 + nt * 16 + lr];
#pragma unroll
            for (int r = 0; r < 4; ++r)
#pragma unroll
                for (int nt = 0; nt < 4; ++nt)
                    cc[r][nt] = (float)chh[(size_t)id[r] * 192 + 128 + nt * 16 + lr];
#pragma unroll
            for (int r = 0; r < 4; ++r)
#pragma unroll
                for (int nt = 0; nt < 4; ++nt) {
                    const float h = (float)(short)(hg[r][nt] & 0xFFFFu) * (1.f / 32767.f);
                    const float g = (float)((int)hg[r][nt] >> 16) * (1.f / 2048.f);
                    hs[r][nt] += h;
                    bfv[r][nt] = fmaf(sigm(wfx[r][nt] + g), cc[r][nt], bfv[r][nt]);
                }
        }
    }
    // hsum -> LDS A-tile, split hi/lo bf16 (|hs|<=16 is precision-critical)
#pragma unroll
    for (int r = 0; r < 4; ++r)
#pragma unroll
        for (int nt = 0; nt < 4; ++nt) {
            const int m = wv * 16 + qd * 4 + r, col = nt * 16 + lr;
            const unsigned short hi = f2bf(hs[r][nt]);
            Ah[m][col] = hi;
            AlHs[m][col] = f2bf(hs[r][nt] - bf2f(hi));
        }
    __syncthreads();

    // ---- iuo GEMM: split-bf16 A x bf16 B, fp32 acc
    short8 ah[2], al[2];
#pragma unroll
    for (int ks = 0; ks < 2; ++ks) {
        ah[ks] = *(const short8*)&Ah[wv * 16 + lr][ks * 32 + qd * 8];
        al[ks] = *(const short8*)&AlHs[wv * 16 + lr][ks * 32 + qd * 8];
    }
    floatx4 ai[4], au[4], ao[4];
#pragma unroll
    for (int nt = 0; nt < 4; ++nt) {
        ai[nt] = (floatx4){0.f, 0.f, 0.f, 0.f};
        au[nt] = (floatx4){0.f, 0.f, 0.f, 0.f};
        ao[nt] = (floatx4){0.f, 0.f, 0.f, 0.f};
    }
#pragma unroll
    for (int nt = 0; nt < 4; ++nt) {
#pragma unroll
        for (int ks = 0; ks < 2; ++ks) {
            short8 b0 = *(const short8*)&Bi[nt * 16 + lr][ks * 32 + qd * 8];
            short8 b1 = *(const short8*)&Bi[64 + nt * 16 + lr][ks * 32 + qd * 8];
            short8 b2 = *(const short8*)&Bi[128 + nt * 16 + lr][ks * 32 + qd * 8];
            ai[nt] = __builtin_amdgcn_mfma_f32_16x16x32_bf16(al[ks], b0, ai[nt], 0, 0, 0);
            ai[nt] = __builtin_amdgcn_mfma_f32_16x16x32_bf16(ah[ks], b0, ai[nt], 0, 0, 0);
            au[nt] = __builtin_amdgcn_mfma_f32_16x16x32_bf16(al[ks], b1, au[nt], 0, 0, 0);
            au[nt] = __builtin_amdgcn_mfma_f32_16x16x32_bf16(ah[ks], b1, au[nt], 0, 0, 0);
            ao[nt] = __builtin_amdgcn_mfma_f32_16x16x32_bf16(al[ks], b2, ao[nt], 0, 0, 0);
            ao[nt] = __builtin_amdgcn_mfma_f32_16x16x32_bf16(ah[ks], b2, ao[nt], 0, 0, 0);
        }
    }
    // ---- gate epilogue (bf is a register; c stored fp16; nh restaged in LDS)
    float nhv[4][4];
#pragma unroll
    for (int nt = 0; nt < 4; ++nt) {
        const int col = nt * 16 + lr;
#pragma unroll
        for (int r = 0; r < 4; ++r) {
            const int node = n0 + wv * 16 + qd * 4 + r;
            const float* __restrict__ wxr = Wx + (size_t)node * 256;
            const float ig = sigm(ai[nt][r] + wxr[64 + col]);
            const float ug = ftanh(au[nt][r] + wxr[128 + col]);
            const float og = sigm(ao[nt][r] + wxr[192 + col]);
            const float nc = fmaf(ig, ug, bfv[r][nt]);
            const float nh = og * ftanh(nc);
            nhv[nt][r] = nh;
            if (last) {
                out[(size_t)node * 64 + col] = nh;
            } else {
                ((_Float16*)snext)[(size_t)(node + 1) * 192 + 128 + col] = (_Float16)nc;
                AlHs[wv * 16 + qd * 4 + r][col] = f2bf(nh);  // Al is dead: reuse
            }
        }
    }
    if (!last) {
        // ---- g = nh @ U_f (wave-private LDS tile; compiler inserts lgkmcnt wait)
        short8 ag[2];
#pragma unroll
        for (int ks = 0; ks < 2; ++ks)
            ag[ks] = *(const short8*)&AlHs[wv * 16 + lr][ks * 32 + qd * 8];
        floatx4 g[4];
#pragma unroll
        for (int nt = 0; nt < 4; ++nt) g[nt] = (floatx4){0.f, 0.f, 0.f, 0.f};
#pragma unroll
        for (int nt = 0; nt < 4; ++nt) {
#pragma unroll
            for (int ks = 0; ks < 2; ++ks) {
                short8 bfr = *(const short8*)&Bf[nt * 16 + lr][ks * 32 + qd * 8];
                g[nt] = __builtin_amdgcn_mfma_f32_16x16x32_bf16(ag[ks], bfr, g[nt], 0, 0, 0);
            }
        }
        unsigned* __restrict__ su = (unsigned*)snext;
#pragma unroll
        for (int nt = 0; nt < 4; ++nt) {
#pragma unroll
            for (int r = 0; r < 4; ++r) {
                const int node = n0 + wv * 16 + qd * 4 + r;
                // |nh|<1 (o*tanh), |g|<=8 (sum |h|*|U_f| <= 64*1*0.125)
                const int hq = (int)rintf(nhv[nt][r] * 32767.f);
                const int gq = (int)rintf(g[nt][r] * 2048.f);
                su[(size_t)(node + 1) * 96 + nt * 16 + lr] =
                    ((unsigned)hq & 0xFFFFu) | ((unsigned)gq << 16);
            }
        }
        if (blockIdx.x == 0 && tid < 96)
            ((unsigned*)snext)[tid] = 0u;   // zero init-state row (h,g,c=0)
    }
}

extern "C" void kernel_launch(void* const* d_in, const int* in_sizes, int n_in,
                              void* d_out, int out_size, void* d_ws, size_t ws_size,
                              hipStream_t stream)
{
    const int*   labels = (const int*)d_in[0];    // [6, 32768]
    const int*   child  = (const int*)d_in[1];    // [6, 32768, 16]
    const float* E      = (const float*)d_in[2];  // [100000, 64]
    const float* W_w    = (const float*)d_in[3];  // [64, 256]
    const float* W_b    = (const float*)d_in[4];  // [256]
    const float* U_f    = (const float*)d_in[5];  // [64, 64]
    const float* U_iuo  = (const float*)d_in[6];  // [64, 192]
    float* out = (float*)d_out;
    float* ws  = (float*)d_ws;

    // ws layout (ws_size = 256 MiB, evidenced by the 262144-KB re-poison fill):
    //   s0, s1: 32769 rows x 384 B = 12.6 MB each (state ping-pong)
    //   WxAll:  [6, N, 256] fp32 = 201.3 MB
    // total 226.5 MB.
    const size_t R = (size_t)(NN + 1) * 96;       // state rows in u32 words
    float* s0    = ws;
    float* s1    = ws + R;
    float* WxAll = ws + 2 * R;

    k0_all<<<6 * (NN / 64), 256, 0, stream>>>(labels, E, W_w, W_b, WxAll);

    float* sp = s0;
    float* sn = s1;
    for (int d = 0; d < DD; ++d) {
        const int last = (d == DD - 1);
        kd_fused<<<NN / 64, 256, 0, stream>>>(
            child + (size_t)d * NN * KK, sp, WxAll + (size_t)d * NN * 256,
            U_iuo, U_f, sn, out, d == 0, last);
        float* ts = sp; sp = sn; sn = ts;
    }
}

// Round 8
// 366.321 us; speedup vs baseline: 3.4499x; 1.0143x over previous
//
#include <hip/hip_runtime.h>

#define NN 32768
#define KK 16
#define DD 6
// State row per node-slot j: 64 x uint2 {hg, c} = 512 B interleaved.
//   .x = (int16)(h*32767) | (int16)(g*2048) << 16      .y = c as fp32 bits
// Row 0 = all zero (child_idx==0 masking is free).
// Wx16: per depth, per node: 256 fp16 pre-activations (f,i,u,o gate order).

typedef short short8 __attribute__((ext_vector_type(8)));
typedef float floatx4 __attribute__((ext_vector_type(4)));

__device__ __forceinline__ float sigm(float x) { return 1.0f / (1.0f + __expf(-x)); }
__device__ __forceinline__ float ftanh(float x) {
    float e = __expf(2.0f * x);
    return 1.0f - 2.0f / (e + 1.0f);
}
__device__ __forceinline__ unsigned short f2bf(float x) {   // RNE fp32->bf16
    union { float f; unsigned u; } v; v.f = x;
    unsigned r = v.u + 0x7FFF + ((v.u >> 16) & 1);
    return (unsigned short)(r >> 16);
}
__device__ __forceinline__ float bf2f(unsigned short h) {
    union { unsigned u; float f; } v; v.u = ((unsigned)h) << 16; return v.f;
}

// ---------------------------------------------------------------------------
// K0_ALL (MFMA): Wx16[dep][n,0:256] = fp16(E[labels[dep][n]] @ W_w + W_b),
// all 6 depths in one launch. Pad 74 (word-stride 37, gcd(37,32)=1) kills the
// R6 staging bank conflicts (1.67M -> ~0). LDS 47.6KB -> 3 blocks/CU.
__global__ __launch_bounds__(256) void k0_all(
    const int* __restrict__ labels, const float* __restrict__ E,
    const float* __restrict__ W_w, const float* __restrict__ W_b,
    _Float16* __restrict__ WxAll)
{
    __shared__ int labs[64];
    __shared__ __align__(16) unsigned short Ax[64][74];
    __shared__ __align__(16) unsigned short Bw[256][74];
    const int tid = threadIdx.x;
    const int blk = blockIdx.x & 511;
    const int dep = blockIdx.x >> 9;
    const int n0 = blk * 64;
    _Float16* __restrict__ Wx = WxAll + (size_t)dep * NN * 256;
    if (tid < 64) labs[tid] = labels[(size_t)dep * NN + n0 + tid];
    __syncthreads();
    {   // stage A: thread -> node m = tid>>2, 16 dims
        const int m = tid >> 2, q = tid & 3;
        const float4* e4 = (const float4*)(E + (size_t)labs[m] * 64 + q * 16);
#pragma unroll
        for (int i = 0; i < 4; ++i) {
            float4 v = e4[i];
            Ax[m][q * 16 + i * 4 + 0] = f2bf(v.x);
            Ax[m][q * 16 + i * 4 + 1] = f2bf(v.y);
            Ax[m][q * 16 + i * 4 + 2] = f2bf(v.z);
            Ax[m][q * 16 + i * 4 + 3] = f2bf(v.w);
        }
    }
    {   // stage B transposed: thread = col, coalesced global reads per k
        const int c = tid;
#pragma unroll 4
        for (int k = 0; k < 64; ++k) Bw[c][k] = f2bf(W_w[k * 256 + c]);
    }
    __syncthreads();
    const int ln = tid & 63, wv = tid >> 6;
    const int lr = ln & 15, qd = ln >> 4;
    short8 af[2];
#pragma unroll
    for (int ks = 0; ks < 2; ++ks)
        af[ks] = *(const short8*)&Ax[wv * 16 + lr][ks * 32 + qd * 8];
    floatx4 acc[16];
#pragma unroll
    for (int nt = 0; nt < 16; ++nt) acc[nt] = (floatx4){0.f, 0.f, 0.f, 0.f};
#pragma unroll
    for (int nt = 0; nt < 16; ++nt) {
#pragma unroll
        for (int ks = 0; ks < 2; ++ks) {
            short8 bw = *(const short8*)&Bw[nt * 16 + lr][ks * 32 + qd * 8];
            acc[nt] = __builtin_amdgcn_mfma_f32_16x16x32_bf16(af[ks], bw, acc[nt], 0, 0, 0);
        }
    }
    // C/D layout: col = lane&15, row = quad*4 + reg. fp16 store (|preact|<10).
#pragma unroll
    for (int nt = 0; nt < 16; ++nt) {
        const int col = nt * 16 + lr;
        const float bb = W_b[col];
#pragma unroll
        for (int r = 0; r < 4; ++r) {
            const int node = n0 + wv * 16 + qd * 4 + r;
            Wx[(size_t)node * 256 + col] = (_Float16)(acc[nt][r] + bb);
        }
    }
}

// ---------------------------------------------------------------------------
// KD: fused gather + iuo-GEMM + gates + g-GEMM + pack store, one per depth.
// Thread (wv,qd,lr) owns nodes {wv*16+qd*4+r} x cols {nt*16+lr} (MFMA C-layout)
// so branch_f / h_sum never round-trip through global.
// Pads 68 -> LDS 52,224 B -> 3 blocks/CU (more waves for the gather phase;
// stride-34 frag reads are <=4-way, better than pad-72's 8-way).
__global__ __launch_bounds__(256) void kd_fused(
    const int* __restrict__ cidx, const uint2* __restrict__ sprev,
    const _Float16* __restrict__ Wx, const float* __restrict__ U_iuo,
    const float* __restrict__ U_f, uint2* __restrict__ snext,
    float* __restrict__ out, int first, int last)
{
    __shared__ __align__(16) unsigned short Bi[192][68];   // U_iuo^T [c][k]
    __shared__ __align__(16) unsigned short Bf[64][68];    // U_f^T   [c][k]
    __shared__ __align__(16) unsigned short Ah[64][68];    // hsum hi
    __shared__ __align__(16) unsigned short AlHs[64][68];  // hsum lo, later nh
    const int tid = threadIdx.x;
    const int n0 = blockIdx.x * 64;
    // stage B matrices (bf16, transposed) -- R6-proven idiom, no ws dependency
    if (tid < 192) {
        const int c = tid;
#pragma unroll 4
        for (int k = 0; k < 64; ++k) Bi[c][k] = f2bf(U_iuo[k * 192 + c]);
    } else {
        const int c = tid - 192;
#pragma unroll 4
        for (int k = 0; k < 64; ++k) Bf[c][k] = f2bf(U_f[k * 64 + c]);
    }
    const int ln = tid & 63, wv = tid >> 6;
    const int lr = ln & 15, qd = ln >> 4;

    // ---- gather phase: hs/bf in C-layout registers
    float hs[4][4] = {{0.f}}, bfv[4][4] = {{0.f}};
    if (!first) {
        float wfx[4][4];
#pragma unroll
        for (int r = 0; r < 4; ++r)
#pragma unroll
            for (int nt = 0; nt < 4; ++nt)
                wfx[r][nt] = (float)Wx[(size_t)(n0 + wv * 16 + qd * 4 + r) * 256
                                       + nt * 16 + lr];
#pragma unroll 1
        for (int k = 0; k < KK; ++k) {
            int id[4];
#pragma unroll
            for (int r = 0; r < 4; ++r)
                id[r] = cidx[(size_t)(n0 + wv * 16 + qd * 4 + r) * KK + k];
            uint2 v[4][4];
#pragma unroll
            for (int r = 0; r < 4; ++r)
#pragma unroll
                for (int nt = 0; nt < 4; ++nt)
                    v[r][nt] = sprev[(size_t)id[r] * 64 + nt * 16 + lr];
#pragma unroll
            for (int r = 0; r < 4; ++r)
#pragma unroll
                for (int nt = 0; nt < 4; ++nt) {
                    const float h = (float)(short)(v[r][nt].x & 0xFFFFu) * (1.f / 32767.f);
                    const float g = (float)((int)v[r][nt].x >> 16) * (1.f / 2048.f);
                    const float c = __uint_as_float(v[r][nt].y);
                    hs[r][nt] += h;
                    bfv[r][nt] = fmaf(sigm(wfx[r][nt] + g), c, bfv[r][nt]);
                }
        }
    }
    // ---- hsum -> LDS A-tile, split hi/lo bf16 (|hs|<=16 precision-critical)
#pragma unroll
    for (int r = 0; r < 4; ++r)
#pragma unroll
        for (int nt = 0; nt < 4; ++nt) {
            const int m = wv * 16 + qd * 4 + r, col = nt * 16 + lr;
            const unsigned short hi = f2bf(hs[r][nt]);
            Ah[m][col] = hi;
            AlHs[m][col] = f2bf(hs[r][nt] - bf2f(hi));
        }
    __syncthreads();
    short8 ah[2], al[2];
#pragma unroll
    for (int ks = 0; ks < 2; ++ks) {
        ah[ks] = *(const short8*)&Ah[wv * 16 + lr][ks * 32 + qd * 8];
        al[ks] = *(const short8*)&AlHs[wv * 16 + lr][ks * 32 + qd * 8];
    }
    // ---- iuo GEMM: acc = hsum @ U_iuo (split-bf16 A, fp32 acc), 12 out-tiles
    floatx4 acc[12];
#pragma unroll
    for (int nt = 0; nt < 12; ++nt) {
        floatx4 a = (floatx4){0.f, 0.f, 0.f, 0.f};
#pragma unroll
        for (int ks = 0; ks < 2; ++ks) {
            const short8 bu = *(const short8*)&Bi[nt * 16 + lr][ks * 32 + qd * 8];
            a = __builtin_amdgcn_mfma_f32_16x16x32_bf16(al[ks], bu, a, 0, 0, 0);
            a = __builtin_amdgcn_mfma_f32_16x16x32_bf16(ah[ks], bu, a, 0, 0, 0);
        }
        acc[nt] = a;
    }
    // ---- gate epilogue (C-layout); keep nh,nc in regs for the packed store
    float nhv[4][4], ncv[4][4];
#pragma unroll
    for (int nt = 0; nt < 4; ++nt) {
        const int col = nt * 16 + lr;
#pragma unroll
        for (int r = 0; r < 4; ++r) {
            const int node = n0 + wv * 16 + qd * 4 + r;
            const _Float16* __restrict__ wxr = Wx + (size_t)node * 256;
            const float ig = sigm(acc[nt][r] + (float)wxr[64 + col]);
            const float ug = ftanh(acc[4 + nt][r] + (float)wxr[128 + col]);
            const float og = sigm(acc[8 + nt][r] + (float)wxr[192 + col]);
            const float nc = fmaf(ig, ug, bfv[r][nt]);
            const float nh = og * ftanh(nc);
            nhv[nt][r] = nh;
            ncv[nt][r] = nc;
            if (last) {
                out[(size_t)node * 64 + col] = nh;
            } else {
                AlHs[wv * 16 + qd * 4 + r][col] = f2bf(nh);  // Al dead: restage nh
            }
        }
    }
    if (!last) {
        // ---- g = nh @ U_f (wave-private LDS tile; lgkmcnt covers the dep)
        short8 ag[2];
#pragma unroll
        for (int ks = 0; ks < 2; ++ks)
            ag[ks] = *(const short8*)&AlHs[wv * 16 + lr][ks * 32 + qd * 8];
        floatx4 g[4];
#pragma unroll
        for (int nt = 0; nt < 4; ++nt) {
            g[nt] = (floatx4){0.f, 0.f, 0.f, 0.f};
#pragma unroll
            for (int ks = 0; ks < 2; ++ks) {
                const short8 bfr = *(const short8*)&Bf[nt * 16 + lr][ks * 32 + qd * 8];
                g[nt] = __builtin_amdgcn_mfma_f32_16x16x32_bf16(ag[ks], bfr, g[nt], 0, 0, 0);
            }
        }
#pragma unroll
        for (int nt = 0; nt < 4; ++nt) {
#pragma unroll
            for (int r = 0; r < 4; ++r) {
                const int node = n0 + wv * 16 + qd * 4 + r;
                // |nh|<1 (o*tanh), |g|<=8 (64 * 1 * 0.125) -> int16 scales safe
                const int hq = (int)rintf(nhv[nt][r] * 32767.f);
                const int gq = (int)rintf(g[nt][r] * 2048.f);
                uint2 pw;
                pw.x = ((unsigned)hq & 0xFFFFu) | ((unsigned)gq << 16);
                pw.y = __float_as_uint(ncv[nt][r]);
                snext[(size_t)(node + 1) * 64 + nt * 16 + lr] = pw;
            }
        }
        if (blockIdx.x == 0 && tid < 64)
            snext[tid] = make_uint2(0u, 0u);   // zero init-state row
    }
}

extern "C" void kernel_launch(void* const* d_in, const int* in_sizes, int n_in,
                              void* d_out, int out_size, void* d_ws, size_t ws_size,
                              hipStream_t stream)
{
    const int*   labels = (const int*)d_in[0];    // [6, 32768]
    const int*   child  = (const int*)d_in[1];    // [6, 32768, 16]
    const float* E      = (const float*)d_in[2];  // [100000, 64]
    const float* W_w    = (const float*)d_in[3];  // [64, 256]
    const float* W_b    = (const float*)d_in[4];  // [256]
    const float* U_f    = (const float*)d_in[5];  // [64, 64]
    const float* U_iuo  = (const float*)d_in[6];  // [64, 192]
    float* out = (float*)d_out;

    // ws: s0,s1 = (NN+1)*512 B state ping-pong (16.8 MB each);
    //     WxAll = 6*NN*256 fp16 = 100.7 MB. Total ~134 MB < 256 MiB.
    uint2* s0 = (uint2*)d_ws;
    uint2* s1 = s0 + (size_t)(NN + 1) * 64;
    _Float16* WxAll = (_Float16*)(s1 + (size_t)(NN + 1) * 64);

    k0_all<<<6 * (NN / 64), 256, 0, stream>>>(labels, E, W_w, W_b, WxAll);

    uint2* sp = s0;
    uint2* sn = s1;
    for (int d = 0; d < DD; ++d) {
        const int last = (d == DD - 1);
        kd_fused<<<NN / 64, 256, 0, stream>>>(
            child + (size_t)d * NN * KK, sp, WxAll + (size_t)d * NN * 256,
            U_iuo, U_f, sn, out, d == 0, last);
        uint2* ts = sp; sp = sn; sn = ts;
    }
}